// Round 5
// baseline (366.396 us; speedup 1.0000x reference)
//
#include <hip/hip_runtime.h>

// Hidden-size-1 LSTM, B=32768 chains, 1024 open + 512 closed steps.
// TWO LANES PER CHAIN (even: gates i,g; odd: gates f,o), DPP pair-exchange.
// 1024 waves (32 chains each), 1 wave/SIMD: latency-bound regime, so the
// design minimizes (critical-path latency + per-wave issue):
//  - x/t staged to LDS with 16B-aligned rows (PAD=68) -> ds_read_b128,
//    one read per 4 steps, distance-1 prefetch into registers
//  - zx = fma(x,A,C) hoisted off the critical path per 4-step group
//  - preds: 1 ds_write_b32/step + coalesced per-chunk flush (R3's 71MB write)
// c kept pre-scaled: C = 2*log2(e)*c, so tanh(c) = 1 - 2*rcp(1+exp2(C)).
// sigma(z) = rcp(1+exp2(-L2E*z)); tanh(z) = 1 - 2*rcp(1+exp2(2*L2E*z)).

#define L2E 1.44269504088896340736f
#define B_TOT 32768
#define T_IN 1024
#define STEPS 512
#define CPB 32          // chains per block (one wave, 2 lanes/chain)
#define CH 64           // chunk length in steps
#define PAD 68          // LDS row stride: 272B, 16B-aligned -> b128 ops

__device__ __forceinline__ float ex2(float x){ return __builtin_amdgcn_exp2f(x); }
__device__ __forceinline__ float rcp(float x){ return __builtin_amdgcn_rcpf(x); }
__device__ __forceinline__ float dpp_swap1(float v){
    // quad_perm [1,0,3,2]: swap adjacent lanes within each quad
    return __int_as_float(__builtin_amdgcn_mov_dpp(__float_as_int(v), 0xB1, 0xF, 0xF, true));
}

struct LaneK { float A1,B1,C1, A2,B2,C2, W1,W2; };

// even lane: z1 = i-gate (-L2E scale), z2 = g-gate (+2*L2E scale)
// odd  lane: z1 = f-gate, z2 = o-gate
__device__ __forceinline__ void tail(float z1, float z2, bool odd,
                                     float& h, float& C){
    float r1 = rcp(1.0f + ex2(z1));
    float r2 = rcp(1.0f + ex2(z2));
    float s1 = dpp_swap1(r1);
    float s2 = dpp_swap1(r2);
    float ri = odd ? s1 : r1;     // sigma(zi)
    float rf = odd ? r1 : s1;     // sigma(zf)
    float rg = odd ? s2 : r2;     // 1/(1+e^{2 zg})
    float ro = odd ? r2 : s2;     // sigma(zo)
    float g2 = fmaf(rg, -4.0f * L2E, 2.0f * L2E);   // 2*L2E*tanh(g)
    C = fmaf(rf, C, ri * g2);                        // C = 2*L2E*c_new
    float rc = rcp(1.0f + ex2(C));
    float u  = rc + rc;
    h = fmaf(-u, ro, ro);                            // h = ro*(1-2rc)
}

// stage a 32-row x 64-col chunk: 8 float4/lane, coalesced global reads
__device__ __forceinline__ void stage_issue32(const float* __restrict__ base,
                                              int rs, int col0, int lane, float4* v){
    const int r_lo = lane >> 4, c4 = lane & 15;
    #pragma unroll
    for (int j = 0; j < 8; ++j)
        v[j] = *(const float4*)(base + (size_t)(j*4 + r_lo) * rs + col0 + c4*4);
}
__device__ __forceinline__ void stage_write32(float* __restrict__ lds, int lane,
                                              const float4* v){
    const int r_lo = lane >> 4, c4 = lane & 15;
    #pragma unroll
    for (int j = 0; j < 8; ++j)
        *(float4*)(lds + (j*4 + r_lo) * PAD + c4*4) = v[j];   // 16B-aligned
}

__global__ __launch_bounds__(64) void lstm_chain_kernel(
    const float* __restrict__ x, const float* __restrict__ t,
    const float* __restrict__ h0, const float* __restrict__ c0,
    const float* __restrict__ w_ih, const float* __restrict__ w_hh,
    const float* __restrict__ b_ih, const float* __restrict__ b_hh,
    float* __restrict__ out)
{
    __shared__ float sb[2][CPB * PAD];   // x/t staging, double-buffered
    __shared__ float pb[CPB * PAD];      // pred staging

    const int lane = threadIdx.x;
    const bool odd = lane & 1;
    const int ch   = lane >> 1;          // chain within block (0..31)
    const int b0   = blockIdx.x * CPB;

    LaneK K;
    {
        float bi = b_ih[0] + b_hh[0], bf = b_ih[1] + b_hh[1];
        float bg = b_ih[2] + b_hh[2], bo = b_ih[3] + b_hh[3];
        float Ai = -L2E*w_ih[0], Bi = -L2E*w_hh[0], Ci = -L2E*bi;
        float Af = -L2E*w_ih[1], Bf = -L2E*w_hh[1], Cf = -L2E*bf;
        float Ag = 2.0f*L2E*w_ih[2], Bg = 2.0f*L2E*w_hh[2], Cg = 2.0f*L2E*bg;
        float Ao = -L2E*w_ih[3], Bo = -L2E*w_hh[3], Co = -L2E*bo;
        K.A1 = odd ? Af : Ai;  K.B1 = odd ? Bf : Bi;  K.C1 = odd ? Cf : Ci;
        K.A2 = odd ? Ao : Ag;  K.B2 = odd ? Bo : Bg;  K.C2 = odd ? Co : Cg;
        K.W1 = K.A1 + K.B1;    K.W2 = K.A2 + K.B2;    // closed loop: x_in = h
    }

    float h = h0[b0 + ch];
    float C = (2.0f * L2E) * c0[b0 + ch];

    const float* xbase = x + (size_t)b0 * T_IN;
    const float* tbase = t + (size_t)b0 * STEPS;

    // ---- open loop: 16 chunks of 64 steps ----
    { float4 stg[8]; stage_issue32(xbase, T_IN, 0, lane, stg); stage_write32(sb[0], lane, stg); }
    #pragma unroll 1
    for (int k = 0; k < T_IN / CH; ++k){
        float4 stg[8];
        if (k < T_IN/CH - 1) stage_issue32(xbase, T_IN, (k+1)*CH, lane, stg);
        const float4* xr4 = (const float4*)(&sb[k & 1][ch * PAD]);
        float4 q = xr4[0];
        #pragma unroll 1
        for (int j = 0; j < 16; ++j){
            float4 qn = xr4[(j < 15) ? (j + 1) : 15];   // distance-1 prefetch
            // x-side gate partials: independent, off the critical path
            float za1 = fmaf(q.x, K.A1, K.C1), za2 = fmaf(q.x, K.A2, K.C2);
            float zb1 = fmaf(q.y, K.A1, K.C1), zb2 = fmaf(q.y, K.A2, K.C2);
            float zc1 = fmaf(q.z, K.A1, K.C1), zc2 = fmaf(q.z, K.A2, K.C2);
            float zd1 = fmaf(q.w, K.A1, K.C1), zd2 = fmaf(q.w, K.A2, K.C2);
            tail(fmaf(h, K.B1, za1), fmaf(h, K.B2, za2), odd, h, C);
            tail(fmaf(h, K.B1, zb1), fmaf(h, K.B2, zb2), odd, h, C);
            tail(fmaf(h, K.B1, zc1), fmaf(h, K.B2, zc2), odd, h, C);
            tail(fmaf(h, K.B1, zd1), fmaf(h, K.B2, zd2), odd, h, C);
            q = qn;
        }
        if (k < T_IN/CH - 1) stage_write32(sb[(k+1) & 1], lane, stg);
    }
    float xin = sb[1][ch * PAD + (CH - 1)];   // x[b,1023] (chunk 15 -> buf 1)

    // ---- closed loop: 8 chunks of 64 steps ----
    { float4 stg[8]; stage_issue32(tbase, STEPS, 0, lane, stg); stage_write32(sb[0], lane, stg); }
    float lacc = 0.0f;
    #pragma unroll 1
    for (int k = 0; k < STEPS / CH; ++k){
        float4 stg[8];
        if (k < STEPS/CH - 1) stage_issue32(tbase, STEPS, (k+1)*CH, lane, stg);
        const float4* tr4 = (const float4*)(&sb[k & 1][ch * PAD]);
        float* prow = &pb[ch * PAD];
        float4 q = tr4[0];
        #pragma unroll 1
        for (int j = 0; j < 16; ++j){
            float4 qn = tr4[(j < 15) ? (j + 1) : 15];
            float d;
            if (k == 0 && j == 0)   // first closed step feeds x[b,1023]
                tail(fmaf(xin, K.A1, fmaf(h, K.B1, K.C1)),
                     fmaf(xin, K.A2, fmaf(h, K.B2, K.C2)), odd, h, C);
            else
                tail(fmaf(h, K.W1, K.C1), fmaf(h, K.W2, K.C2), odd, h, C);
            d = h - q.x; lacc = fmaf(d, d, lacc); prow[j*4 + 0] = h;
            tail(fmaf(h, K.W1, K.C1), fmaf(h, K.W2, K.C2), odd, h, C);
            d = h - q.y; lacc = fmaf(d, d, lacc); prow[j*4 + 1] = h;
            tail(fmaf(h, K.W1, K.C1), fmaf(h, K.W2, K.C2), odd, h, C);
            d = h - q.z; lacc = fmaf(d, d, lacc); prow[j*4 + 2] = h;
            tail(fmaf(h, K.W1, K.C1), fmaf(h, K.W2, K.C2), odd, h, C);
            d = h - q.w; lacc = fmaf(d, d, lacc); prow[j*4 + 3] = h;
            q = qn;
        }
        // flush preds: 32 rows, 64 consecutive dwords per store instruction
        float* obase = out + 1 + (size_t)b0 * STEPS + k * CH;
        #pragma unroll 4
        for (int r = 0; r < CPB; ++r)
            obase[(size_t)r * STEPS + lane] = pb[r * PAD + lane];
        if (k < STEPS/CH - 1) stage_write32(sb[(k+1) & 1], lane, stg);
    }

    // ---- loss: both lanes of a pair hold identical lacc -> scale by 0.5 ----
    #pragma unroll
    for (int off = 32; off > 0; off >>= 1)
        lacc += __shfl_down(lacc, off, 64);
    if (lane == 0)
        atomicAdd(out, lacc * (0.5f / (float)B_TOT));
}

extern "C" void kernel_launch(void* const* d_in, const int* in_sizes, int n_in,
                              void* d_out, int out_size, void* d_ws, size_t ws_size,
                              hipStream_t stream) {
    const float* x    = (const float*)d_in[0];
    const float* t    = (const float*)d_in[1];
    const float* h0   = (const float*)d_in[2];
    const float* c0   = (const float*)d_in[3];
    const float* w_ih = (const float*)d_in[4];
    const float* w_hh = (const float*)d_in[5];
    const float* b_ih = (const float*)d_in[6];
    const float* b_hh = (const float*)d_in[7];
    float* out = (float*)d_out;

    hipMemsetAsync(out, 0, sizeof(float), stream);

    lstm_chain_kernel<<<B_TOT / CPB, 64, 0, stream>>>(
        x, t, h0, c0, w_ih, w_hh, b_ih, b_hh, out);
}

// Round 6
// 316.760 us; speedup vs baseline: 1.1567x; 1.1567x over previous
//
#include <hip/hip_runtime.h>

// Hidden-size-1 LSTM, B=32768 chains, 1024 open + 512 closed steps.
// R3 structure (the measured best: 152us) + micro-opts only:
//  - 2 lanes/chain (even: gates i,g; odd: f,o), 1024 waves = 1 wave/SIMD
//  - DPP quad_perm pair-BROADCASTS (0xA0 even-member, 0xF5 odd-member)
//    replace swap+4 selects: fewer issue slots, shorter critical path
//  - h = fma(-rc, ro+ro, ro): ro+ro runs parallel to the rcp
//  - loss fused into the flush phase (coalesced LDS reads), NOT in the
//    serial step loop: steps only ds_write h
//  - x/t staged via LDS exactly as R3 (PAD=65, scalar reads, dbuf)
// c pre-scaled: C = 2*log2(e)*c, so tanh(c) = 1 - 2*rcp(1+exp2(C)).
// sigma(z) = rcp(1+exp2(-L2E*z)); tanh(z) = 1 - 2*rcp(1+exp2(2*L2E*z)).

#define L2E 1.44269504088896340736f
#define B_TOT 32768
#define T_IN 1024
#define STEPS 512
#define CPB 32          // chains per block (one wave, 2 lanes/chain)
#define CH 64           // chunk length in steps
#define PAD 65          // LDS row stride: bank = (chain + s) % 32

__device__ __forceinline__ float ex2(float x){ return __builtin_amdgcn_exp2f(x); }
__device__ __forceinline__ float rcp(float x){ return __builtin_amdgcn_rcpf(x); }
template<int CTRL>
__device__ __forceinline__ float qp(float v){
    // quad_perm broadcast: 0xA0 -> lanes {0,1}<-0,{2,3}<-2 (even pair member)
    //                      0xF5 -> lanes {0,1}<-1,{2,3}<-3 (odd pair member)
    return __int_as_float(__builtin_amdgcn_mov_dpp(__float_as_int(v), CTRL, 0xF, 0xF, true));
}

struct LaneK { float A1,B1,C1, A2,B2,C2, W1,W2; };

// even lane: z1 = i-gate (-L2E scale), z2 = g-gate (+2*L2E scale)
// odd  lane: z1 = f-gate,              z2 = o-gate
__device__ __forceinline__ void tail(float z1, float z2, float& h, float& C){
    float r1 = rcp(1.0f + ex2(z1));
    float r2 = rcp(1.0f + ex2(z2));
    float ri = qp<0xA0>(r1);      // sigma(zi)  (even member's r1)
    float rf = qp<0xF5>(r1);      // sigma(zf)  (odd member's r1)
    float rg = qp<0xA0>(r2);      // 1/(1+e^{2 zg})
    float ro = qp<0xF5>(r2);      // sigma(zo)
    float g2 = fmaf(rg, -4.0f * L2E, 2.0f * L2E);   // 2*L2E*tanh(g)
    C = fmaf(rf, C, ri * g2);                        // C = 2*L2E*c_new
    float e   = ex2(C);
    float ro2 = ro + ro;          // parallel with the rcp below
    float rc  = rcp(1.0f + e);
    h = fmaf(-rc, ro2, ro);       // h = ro*(1-2rc)
}

// stage a 32-row x 64-col chunk: 8 float4/lane, coalesced global reads
__device__ __forceinline__ void stage_issue32(const float* __restrict__ base,
                                              int rs, int col0, int lane, float4* v){
    const int r_lo = lane >> 4, c4 = lane & 15;
    #pragma unroll
    for (int j = 0; j < 8; ++j)
        v[j] = *(const float4*)(base + (size_t)(j*4 + r_lo) * rs + col0 + c4*4);
}
__device__ __forceinline__ void stage_write32(float* __restrict__ lds, int lane,
                                              const float4* v){
    const int r_lo = lane >> 4, c4 = lane & 15;
    #pragma unroll
    for (int j = 0; j < 8; ++j){
        float* p = lds + (j*4 + r_lo) * PAD + c4*4;   // rows 4B-aligned (PAD=65)
        p[0]=v[j].x; p[1]=v[j].y; p[2]=v[j].z; p[3]=v[j].w;
    }
}

__global__ __launch_bounds__(64) void lstm_chain_kernel(
    const float* __restrict__ x, const float* __restrict__ t,
    const float* __restrict__ h0, const float* __restrict__ c0,
    const float* __restrict__ w_ih, const float* __restrict__ w_hh,
    const float* __restrict__ b_ih, const float* __restrict__ b_hh,
    float* __restrict__ out)
{
    __shared__ float sb[2][CPB * PAD];   // x/t staging, double-buffered
    __shared__ float pb[CPB * PAD];      // pred staging

    const int lane = threadIdx.x;
    const bool odd = lane & 1;
    const int ch   = lane >> 1;          // chain within block (0..31)
    const int b0   = blockIdx.x * CPB;

    LaneK K;
    {
        float bi = b_ih[0] + b_hh[0], bf = b_ih[1] + b_hh[1];
        float bg = b_ih[2] + b_hh[2], bo = b_ih[3] + b_hh[3];
        float Ai = -L2E*w_ih[0], Bi = -L2E*w_hh[0], Ci = -L2E*bi;
        float Af = -L2E*w_ih[1], Bf = -L2E*w_hh[1], Cf = -L2E*bf;
        float Ag = 2.0f*L2E*w_ih[2], Bg = 2.0f*L2E*w_hh[2], Cg = 2.0f*L2E*bg;
        float Ao = -L2E*w_ih[3], Bo = -L2E*w_hh[3], Co = -L2E*bo;
        K.A1 = odd ? Af : Ai;  K.B1 = odd ? Bf : Bi;  K.C1 = odd ? Cf : Ci;
        K.A2 = odd ? Ao : Ag;  K.B2 = odd ? Bo : Bg;  K.C2 = odd ? Co : Cg;
        K.W1 = K.A1 + K.B1;    K.W2 = K.A2 + K.B2;    // closed loop: x_in = h
    }

    float h = h0[b0 + ch];
    float C = (2.0f * L2E) * c0[b0 + ch];

    const float* xbase = x + (size_t)b0 * T_IN;
    const float* tbase = t + (size_t)b0 * STEPS;

    // ---- open loop: 16 chunks of 64 steps ----
    { float4 stg[8]; stage_issue32(xbase, T_IN, 0, lane, stg); stage_write32(sb[0], lane, stg); }
    #pragma unroll 1
    for (int k = 0; k < T_IN / CH; ++k){
        float4 stg[8];
        if (k < T_IN/CH - 1) stage_issue32(xbase, T_IN, (k+1)*CH, lane, stg);
        const float* xrow = &sb[k & 1][ch * PAD];
        #pragma unroll 8
        for (int s = 0; s < CH; ++s){
            float xv = xrow[s];
            // x-side FMA off the h-critical path
            float z1 = fmaf(h, K.B1, fmaf(xv, K.A1, K.C1));
            float z2 = fmaf(h, K.B2, fmaf(xv, K.A2, K.C2));
            tail(z1, z2, h, C);
        }
        if (k < T_IN/CH - 1) stage_write32(sb[(k+1) & 1], lane, stg);
    }
    float xin = sb[1][ch * PAD + (CH - 1)];   // x[b,1023] (chunk 15 -> buf 1)

    // ---- closed loop: 8 chunks of 64 steps ----
    { float4 stg[8]; stage_issue32(tbase, STEPS, 0, lane, stg); stage_write32(sb[0], lane, stg); }
    float lacc = 0.0f;
    #pragma unroll 1
    for (int k = 0; k < STEPS / CH; ++k){
        float4 stg[8];
        if (k < STEPS/CH - 1) stage_issue32(tbase, STEPS, (k+1)*CH, lane, stg);
        float* prow = &pb[ch * PAD];
        if (k == 0){
            // first closed step feeds x[b,1023], not h
            tail(fmaf(h, K.B1, fmaf(xin, K.A1, K.C1)),
                 fmaf(h, K.B2, fmaf(xin, K.A2, K.C2)), h, C);
            prow[0] = h;
            #pragma unroll 8
            for (int s = 1; s < CH; ++s){
                tail(fmaf(h, K.W1, K.C1), fmaf(h, K.W2, K.C2), h, C);
                prow[s] = h;
            }
        } else {
            #pragma unroll 8
            for (int s = 0; s < CH; ++s){
                tail(fmaf(h, K.W1, K.C1), fmaf(h, K.W2, K.C2), h, C);
                prow[s] = h;
            }
        }
        // flush + fused loss: coalesced LDS reads (bank = (r+lane)%32),
        // 64 consecutive dwords per global store instruction
        const float* trow = &sb[k & 1][0];
        float* obase = out + 1 + (size_t)b0 * STEPS + k * CH;
        #pragma unroll 4
        for (int r = 0; r < CPB; ++r){
            float p  = pb[r * PAD + lane];
            float tv = trow[r * PAD + lane];
            float d  = p - tv;
            lacc = fmaf(d, d, lacc);
            obase[(size_t)r * STEPS + lane] = p;
        }
        if (k < STEPS/CH - 1) stage_write32(sb[(k+1) & 1], lane, stg);
    }

    // ---- loss: each (chain, step) counted exactly once -> scale 1/B ----
    #pragma unroll
    for (int off = 32; off > 0; off >>= 1)
        lacc += __shfl_down(lacc, off, 64);
    if (lane == 0)
        atomicAdd(out, lacc * (1.0f / (float)B_TOT));
}

extern "C" void kernel_launch(void* const* d_in, const int* in_sizes, int n_in,
                              void* d_out, int out_size, void* d_ws, size_t ws_size,
                              hipStream_t stream) {
    const float* x    = (const float*)d_in[0];
    const float* t    = (const float*)d_in[1];
    const float* h0   = (const float*)d_in[2];
    const float* c0   = (const float*)d_in[3];
    const float* w_ih = (const float*)d_in[4];
    const float* w_hh = (const float*)d_in[5];
    const float* b_ih = (const float*)d_in[6];
    const float* b_hh = (const float*)d_in[7];
    float* out = (float*)d_out;

    hipMemsetAsync(out, 0, sizeof(float), stream);

    lstm_chain_kernel<<<B_TOT / CPB, 64, 0, stream>>>(
        x, t, h0, c0, w_ih, w_hh, b_ih, b_hh, out);
}